// Round 1
// baseline (1979.234 us; speedup 1.0000x reference)
//
#include <hip/hip_runtime.h>

#define BB 8
#define CC 3
#define HH 512
#define WW 512
#define OO 64
#define KK 9

__device__ __forceinline__ float samp(const float* __restrict__ xc, int y, int x_) {
    if ((unsigned)y < (unsigned)HH && (unsigned)x_ < (unsigned)WW)
        return xc[y * WW + x_];
    return 0.f;
}

__global__ __launch_bounds__(256) void fused_deform_kernel(
    const float* __restrict__ x,
    const float* __restrict__ w_simple,
    const float* __restrict__ w_off,
    const float* __restrict__ b_off,
    const float* __restrict__ w_mask,
    const float* __restrict__ b_mask,
    float* __restrict__ out)
{
    // Weights staged to LDS, each row padded 27 -> 28 floats so dots run as 7x float4.
    __shared__ __align__(16) float s_woff[18 * 28];
    __shared__ __align__(16) float s_wmsk[9 * 28];
    __shared__ __align__(16) float s_w[64 * 28];
    __shared__ float s_boff[18];
    __shared__ float s_bmsk[9];

    const int tid = threadIdx.x;
    for (int t = tid; t < 18 * 28; t += 256) { int j = t / 28, i = t % 28; s_woff[t] = (i < 27) ? w_off[j * 27 + i] : 0.f; }
    for (int t = tid; t < 9 * 28; t += 256)  { int j = t / 28, i = t % 28; s_wmsk[t] = (i < 27) ? w_mask[j * 27 + i] : 0.f; }
    for (int t = tid; t < 64 * 28; t += 256) { int j = t / 28, i = t % 28; s_w[t]    = (i < 27) ? w_simple[j * 27 + i] : 0.f; }
    if (tid < 18) s_boff[tid] = b_off[tid];
    if (tid < 9)  s_bmsk[tid] = b_mask[tid];
    __syncthreads();

    const int idx = blockIdx.x * 256 + tid;
    const int w = idx & (WW - 1);
    const int h = (idx >> 9) & (HH - 1);
    const int b = idx >> 18;

    const float* xb = x + (size_t)b * CC * HH * WW;

    // ---- 3x3 neighborhood of x (zero-padded), shared by offset & mask convs ----
    float nb[28];
    #pragma unroll
    for (int c = 0; c < CC; ++c) {
        const float* xc = xb + c * HH * WW;
        #pragma unroll
        for (int i = 0; i < 9; ++i) {
            int yy = h - 1 + i / 3;
            int xx = w - 1 + i % 3;
            float v = 0.f;
            if ((unsigned)yy < (unsigned)HH && (unsigned)xx < (unsigned)WW)
                v = xc[yy * WW + xx];
            nb[c * 9 + i] = v;
        }
    }
    nb[27] = 0.f;

    // ---- offset conv (18 ch) ----
    float offv[18];
    #pragma unroll
    for (int j = 0; j < 18; ++j) {
        float acc = s_boff[j];
        const float4* wp = (const float4*)(s_woff + j * 28);
        #pragma unroll
        for (int q = 0; q < 7; ++q) {
            float4 wq = wp[q];
            acc = fmaf(wq.x, nb[q * 4 + 0], acc);
            acc = fmaf(wq.y, nb[q * 4 + 1], acc);
            acc = fmaf(wq.z, nb[q * 4 + 2], acc);
            acc = fmaf(wq.w, nb[q * 4 + 3], acc);
        }
        offv[j] = acc;
    }

    // ---- mask conv (9 ch) + sigmoid ----
    float mval[9];
    #pragma unroll
    for (int j = 0; j < 9; ++j) {
        float acc = s_bmsk[j];
        const float4* wp = (const float4*)(s_wmsk + j * 28);
        #pragma unroll
        for (int q = 0; q < 7; ++q) {
            float4 wq = wp[q];
            acc = fmaf(wq.x, nb[q * 4 + 0], acc);
            acc = fmaf(wq.y, nb[q * 4 + 1], acc);
            acc = fmaf(wq.z, nb[q * 4 + 2], acc);
            acc = fmaf(wq.w, nb[q * 4 + 3], acc);
        }
        mval[j] = 1.f / (1.f + expf(-acc));
    }

    // ---- deformable bilinear sampling, v[c*9+k] = mask_k * bilinear(x_c, py, px) ----
    float vv[28];
    vv[27] = 0.f;
    #pragma unroll
    for (int k = 0; k < 9; ++k) {
        float py = (float)(h - 1 + k / 3) + offv[2 * k + 0];
        float px = (float)(w - 1 + k % 3) + offv[2 * k + 1];
        float y0f = floorf(py);
        float x0f = floorf(px);
        float ty = py - y0f;
        float tx = px - x0f;
        int y0 = (int)y0f;
        int x0 = (int)x0f;
        float w00 = (1.f - ty) * (1.f - tx);
        float w01 = (1.f - ty) * tx;
        float w10 = ty * (1.f - tx);
        float w11 = ty * tx;
        float mk = mval[k];
        #pragma unroll
        for (int c = 0; c < CC; ++c) {
            const float* xc = xb + c * HH * WW;
            float s = 0.f;
            s = fmaf(w00, samp(xc, y0,     x0    ), s);
            s = fmaf(w01, samp(xc, y0,     x0 + 1), s);
            s = fmaf(w10, samp(xc, y0 + 1, x0    ), s);
            s = fmaf(w11, samp(xc, y0 + 1, x0 + 1), s);
            vv[c * 9 + k] = mk * s;
        }
    }

    // ---- einsum: out[b,o,h,w] = sum_{c,k} w_simple[o,c,k] * v[c,k] ----
    const size_t obase = (size_t)b * OO * HH * WW + (size_t)h * WW + w;
    #pragma unroll 4
    for (int o = 0; o < OO; ++o) {
        float acc = 0.f;
        const float4* wp = (const float4*)(s_w + o * 28);
        #pragma unroll
        for (int q = 0; q < 7; ++q) {
            float4 wq = wp[q];
            acc = fmaf(wq.x, vv[q * 4 + 0], acc);
            acc = fmaf(wq.y, vv[q * 4 + 1], acc);
            acc = fmaf(wq.z, vv[q * 4 + 2], acc);
            acc = fmaf(wq.w, vv[q * 4 + 3], acc);
        }
        out[obase + (size_t)o * HH * WW] = acc;
    }
}

extern "C" void kernel_launch(void* const* d_in, const int* in_sizes, int n_in,
                              void* d_out, int out_size, void* d_ws, size_t ws_size,
                              hipStream_t stream) {
    const float* x        = (const float*)d_in[0];
    const float* w_simple = (const float*)d_in[1];
    const float* w_off    = (const float*)d_in[2];
    const float* b_off    = (const float*)d_in[3];
    const float* w_mask   = (const float*)d_in[4];
    const float* b_mask   = (const float*)d_in[5];
    float* out = (float*)d_out;

    const int total = BB * HH * WW;           // 2,097,152 pixels
    const int block = 256;
    const int grid = total / block;           // 8192 blocks
    fused_deform_kernel<<<grid, block, 0, stream>>>(x, w_simple, w_off, b_off, w_mask, b_mask, out);
}